// Round 7
// baseline (182.451 us; speedup 1.0000x reference)
//
#include <hip/hip_runtime.h>

// MechanisticNRTLLoss — B=1e6 samples, scalar fp32 loss.
// R7: global_load_lds DMA staging. Evidence R1-R6: kernel time pinned at
// ~63us regardless of VALU count, coalescing, or offered load concurrency ->
// per-CU fetch cap ~4.1 B/cyc (TCP outstanding-miss limit ~26 lines @ ~450cyc).
// Test: stage all block inputs (34 x 1024B chunks) via global_load_lds_dwordx4
// (DMA path, no VGPR writeback; m97 evidence: >20 B/cyc/CU sustained), one
// barrier, consume from LDS with math identical to R2.

constexpr float ALPHA    = 0.3f;
constexpr float R_GAS    = 8.314462618f;
constexpr float EPS      = 1e-12f;
constexpr float TAU_CLIP = 10.0f;
constexpr float LN_CLIP  = 20.0f;
constexpr float EPS_FD   = 1e-4f;

constexpr float LOG2E = 1.44269504088896340736f;
constexpr float LN2   = 0.69314718055994530942f;

__device__ __forceinline__ float clipf(float v, float lo, float hi) {
    return fminf(fmaxf(v, lo), hi);
}
__device__ __forceinline__ float fast_rcp(float x) { return __builtin_amdgcn_rcpf(x); }

struct Mats {
    float tau[3][3];
    float G[3][3];
    float tG[3][3];
};

__device__ __forceinline__ void ln_gamma3(const float x[3], const Mats& M, float lg[3]) {
    float ratio[3], invd[3];
#pragma unroll
    for (int i = 0; i < 3; ++i) {
        float d = x[0] * M.G[0][i] + x[1] * M.G[1][i] + x[2] * M.G[2][i];
        d = fmaxf(d, EPS);
        float A = x[0] * M.tG[0][i] + x[1] * M.tG[1][i] + x[2] * M.tG[2][i];
        float inv = fast_rcp(d);
        invd[i] = inv;
        ratio[i] = A * inv;
    }
#pragma unroll
    for (int i = 0; i < 3; ++i) {
        float s = ratio[i];
#pragma unroll
        for (int j = 0; j < 3; ++j) {
            s += x[j] * M.G[i][j] * invd[j] * (M.tau[i][j] - ratio[j]);
        }
        lg[i] = clipf(s, -LN_CLIP, LN_CLIP);
    }
}

__device__ __forceinline__ void renorm3(float x[3]) {
    x[0] = fmaxf(x[0], 0.0f);
    x[1] = fmaxf(x[1], 0.0f);
    x[2] = fmaxf(x[2], 0.0f);
    float inv = fast_rcp(fmaxf(x[0] + x[1] + x[2], EPS));
    x[0] *= inv; x[1] *= inv; x[2] *= inv;
}

__global__ __launch_bounds__(256) void nrtl_loss_kernel(
    const float* __restrict__ pred,   // (B,6)
    const float* __restrict__ target, // (B,6)
    const float* __restrict__ Tarr,   // (B,)
    const float* __restrict__ g,      // (B,3,3)
    const float* __restrict__ dirs,   // (2,B,3)
    const float* __restrict__ noise,  // (4,B,3)
    float* __restrict__ partials, int B)
{
    // LDS layout (floats):
    // pred   [0,1536)      target [1536,3072)   g [3072,5376)
    // dirs   [5376,6912)   noise  [6912,9984)   T [9984,10240)
    __shared__ __align__(16) float sh[10240];
    float* s_pred  = sh;
    float* s_targ  = sh + 1536;
    float* s_g     = sh + 3072;
    float* s_dirs  = sh + 5376;
    float* s_noise = sh + 6912;
    float* s_T     = sh + 9984;

    const int t    = threadIdx.x;
    const int wid  = t >> 6;
    const int lane = t & 63;
    const int s0   = blockIdx.x * 256;
    const int ns   = min(256, B - s0);

    if (ns == 256) {
        // ---- DMA staging: 40 chunks x 1024B, round-robin across 4 waves ----
        const float* pb = pred   + (size_t)s0 * 6;
        const float* tb = target + (size_t)s0 * 6;
        const float* gb = g      + (size_t)s0 * 9;
        const float* d0 = dirs  + ((size_t)0 * B + s0) * 3;
        const float* d1 = dirs  + ((size_t)1 * B + s0) * 3;
        const float* n0 = noise + ((size_t)0 * B + s0) * 3;
        const float* n1 = noise + ((size_t)1 * B + s0) * 3;
        const float* n2 = noise + ((size_t)2 * B + s0) * 3;
        const float* n3 = noise + ((size_t)3 * B + s0) * 3;
        const float* Tb = Tarr + s0;

        auto dma = [&](const float* src, int loff) {
            __builtin_amdgcn_global_load_lds(
                (const __attribute__((address_space(1))) unsigned int*)(src + lane * 4),
                (__attribute__((address_space(3))) unsigned int*)(sh + loff),
                16, 0, 0);
        };
        // chunk ids assign waves via (id & 3) == wid
#pragma unroll
        for (int k = 0; k < 6; ++k)  if (((0  + k) & 3) == wid) dma(pb + k * 256, 0    + k * 256);
#pragma unroll
        for (int k = 0; k < 6; ++k)  if (((6  + k) & 3) == wid) dma(tb + k * 256, 1536 + k * 256);
#pragma unroll
        for (int k = 0; k < 9; ++k)  if (((12 + k) & 3) == wid) dma(gb + k * 256, 3072 + k * 256);
#pragma unroll
        for (int k = 0; k < 3; ++k)  if (((21 + k) & 3) == wid) dma(d0 + k * 256, 5376 + k * 256);
#pragma unroll
        for (int k = 0; k < 3; ++k)  if (((24 + k) & 3) == wid) dma(d1 + k * 256, 6144 + k * 256);
#pragma unroll
        for (int k = 0; k < 3; ++k)  if (((27 + k) & 3) == wid) dma(n0 + k * 256, 6912 + k * 256);
#pragma unroll
        for (int k = 0; k < 3; ++k)  if (((30 + k) & 3) == wid) dma(n1 + k * 256, 7680 + k * 256);
#pragma unroll
        for (int k = 0; k < 3; ++k)  if (((33 + k) & 3) == wid) dma(n2 + k * 256, 8448 + k * 256);
#pragma unroll
        for (int k = 0; k < 3; ++k)  if (((36 + k) & 3) == wid) dma(n3 + k * 256, 9216 + k * 256);
        if ((39 & 3) == wid) dma(Tb, 9984);
    } else {
        // ---- tail block: bounds-checked scalar staging ----
        const float* pb = pred   + (size_t)s0 * 6;
        const float* tb = target + (size_t)s0 * 6;
        const float* gb = g      + (size_t)s0 * 9;
        for (int j = t; j < ns * 6; j += 256) { s_pred[j] = pb[j]; s_targ[j] = tb[j]; }
        for (int j = t; j < ns * 9; j += 256) s_g[j] = gb[j];
        for (int d = 0; d < 2; ++d) {
            const float* dg = dirs + ((size_t)d * B + s0) * 3;
            for (int j = t; j < ns * 3; j += 256) s_dirs[d * 768 + j] = dg[j];
        }
        for (int tr = 0; tr < 4; ++tr) {
            const float* ng = noise + ((size_t)tr * B + s0) * 3;
            for (int j = t; j < ns * 3; j += 256) s_noise[tr * 768 + j] = ng[j];
        }
        for (int j = t; j < ns; j += 256) s_T[j] = Tarr[s0 + j];
    }
    __syncthreads();   // drains vmcnt (incl. global_load_lds) + barrier

    const float invB  = 1.0f / (float)B;
    const float SUP_W = invB * (1.0f / 6.0f);
    const float PHY_W = invB * (1.0f / 3.0f);
    const float GD_W  = invB * 0.1f * 0.5f;
    const float TPD_W = invB * 0.1f * 0.25f;

    float contrib = 0.0f;

    if (t < ns) {
        float p6[6], t6[6];
#pragma unroll
        for (int k = 0; k < 6; ++k) { p6[k] = s_pred[t * 6 + k]; t6[k] = s_targ[t * 6 + k]; }
        float sup = 0.0f;
#pragma unroll
        for (int k = 0; k < 6; ++k) { float d = p6[k] - t6[k]; sup += d * d; }
        contrib += SUP_W * sup;

        float xE[3] = {p6[0], p6[1], p6[2]};
        float xR[3] = {p6[3], p6[4], p6[5]};
        renorm3(xE);
        renorm3(xR);

        const float Tc = fmaxf(s_T[t], 1.0f);
        const float invRT = fast_rcp(R_GAS * Tc);
        Mats M;
#pragma unroll
        for (int a = 0; a < 3; ++a) {
#pragma unroll
            for (int b = 0; b < 3; ++b) {
                float ta = clipf(s_g[t * 9 + a * 3 + b] * invRT, -TAU_CLIP, TAU_CLIP);
                float Gv = __builtin_amdgcn_exp2f((-ALPHA * LOG2E) * ta);
                M.tau[a][b] = ta;
                M.G[a][b]   = Gv;
                M.tG[a][b]  = ta * Gv;
            }
        }

        float lgE[3], lgR[3];
        ln_gamma3(xE, M, lgE);
        ln_gamma3(xR, M, lgR);

        float logxE[3];
        float phy = 0.0f;
#pragma unroll
        for (int k = 0; k < 3; ++k) {
            logxE[k] = LN2 * __builtin_amdgcn_logf(fmaxf(xE[k], EPS));
            float logxR = LN2 * __builtin_amdgcn_logf(fmaxf(xR[k], EPS));
            float r = logxE[k] + lgE[k] - logxR - lgR[k];
            phy += r * r;
        }
        contrib += PHY_W * phy;

        float gdsum = 0.0f;
#pragma unroll
        for (int d = 0; d < 2; ++d) {
            float xp[3], xm[3];
#pragma unroll
            for (int k = 0; k < 3; ++k) {
                float dvk = s_dirs[d * 768 + t * 3 + k];
                xp[k] = xE[k] + EPS_FD * dvk;
                xm[k] = xE[k] - EPS_FD * dvk;
            }
            renorm3(xp);
            renorm3(xm);
            float lgp[3], lgm[3];
            ln_gamma3(xp, M, lgp);
            ln_gamma3(xm, M, lgm);
            float gd = 0.0f;
            const float inv2e = 0.5f / EPS_FD;
#pragma unroll
            for (int k = 0; k < 3; ++k) gd += xE[k] * ((lgp[k] - lgm[k]) * inv2e);
            gdsum += gd * gd;
        }
        contrib += GD_W * gdsum;

        float tpdsum = 0.0f;
#pragma unroll
        for (int tr = 0; tr < 4; ++tr) {
            float w[3];
#pragma unroll
            for (int k = 0; k < 3; ++k) w[k] = xE[k] + s_noise[tr * 768 + t * 3 + k];
            renorm3(w);
            float lgw[3];
            ln_gamma3(w, M, lgw);
            float tpd = 0.0f;
#pragma unroll
            for (int k = 0; k < 3; ++k) {
                float logw = LN2 * __builtin_amdgcn_logf(fmaxf(w[k], EPS));
                tpd += w[k] * (logw + lgw[k] - logxE[k] - lgE[k]);
            }
            tpdsum += fmaxf(-tpd, 0.0f);  // MARGIN = 0
        }
        contrib += TPD_W * tpdsum;
    }

    // ---- block reduction ----
#pragma unroll
    for (int off = 32; off > 0; off >>= 1)
        contrib += __shfl_down(contrib, off, 64);

    __shared__ float ssum[4];
    if (lane == 0) ssum[wid] = contrib;
    __syncthreads();
    if (t == 0) partials[blockIdx.x] = ssum[0] + ssum[1] + ssum[2] + ssum[3];
}

__global__ __launch_bounds__(256) void reduce_kernel(
    const float* __restrict__ partials, int n, float* __restrict__ out)
{
    double sacc = 0.0;
    for (int j = threadIdx.x; j < n; j += 256) sacc += (double)partials[j];
#pragma unroll
    for (int off = 32; off > 0; off >>= 1)
        sacc += __shfl_down(sacc, off, 64);
    __shared__ double ds[4];
    const int lane = threadIdx.x & 63;
    const int wid  = threadIdx.x >> 6;
    if (lane == 0) ds[wid] = sacc;
    __syncthreads();
    if (threadIdx.x == 0) out[0] = (float)(ds[0] + ds[1] + ds[2] + ds[3]);
}

extern "C" void kernel_launch(void* const* d_in, const int* in_sizes, int n_in,
                              void* d_out, int out_size, void* d_ws, size_t ws_size,
                              hipStream_t stream) {
    const float* pred   = (const float*)d_in[0];
    const float* target = (const float*)d_in[1];
    const float* Tarr   = (const float*)d_in[2];
    const float* g      = (const float*)d_in[3];
    const float* dirs   = (const float*)d_in[4];
    const float* noise  = (const float*)d_in[5];
    const int B = in_sizes[2];  // T is (B,)

    float* partials = (float*)d_ws;
    float* out      = (float*)d_out;

    const int block = 256;
    const int grid  = (B + block - 1) / block;
    nrtl_loss_kernel<<<grid, block, 0, stream>>>(pred, target, Tarr, g, dirs, noise, partials, B);
    reduce_kernel<<<1, block, 0, stream>>>(partials, grid, out);
}

// Round 9
// 173.757 us; speedup vs baseline: 1.0500x; 1.0500x over previous
//
#include <hip/hip_runtime.h>

// MechanisticNRTLLoss — B=1e6 samples, scalar fp32 loss.
// R9 (= R8 with compile fix): non-temporal loads via ext_vector_type instead
// of HIP_vector_type (the builtin rejects HIP's float2 class). Structure and
// math identical to R2; only load ops carry the nt flag.

constexpr float ALPHA    = 0.3f;
constexpr float R_GAS    = 8.314462618f;
constexpr float EPS      = 1e-12f;
constexpr float TAU_CLIP = 10.0f;
constexpr float LN_CLIP  = 20.0f;
constexpr float EPS_FD   = 1e-4f;

constexpr float LOG2E = 1.44269504088896340736f;
constexpr float LN2   = 0.69314718055994530942f;

typedef float v2f __attribute__((ext_vector_type(2)));

__device__ __forceinline__ float clipf(float v, float lo, float hi) {
    return fminf(fmaxf(v, lo), hi);
}
__device__ __forceinline__ float fast_rcp(float x) { return __builtin_amdgcn_rcpf(x); }
__device__ __forceinline__ v2f nt_load2(const float* p) {
    return __builtin_nontemporal_load((const v2f*)p);
}
__device__ __forceinline__ float nt_load(const float* p) {
    return __builtin_nontemporal_load(p);
}

struct Mats {
    float tau[3][3];
    float G[3][3];
    float tG[3][3];
};

__device__ __forceinline__ void ln_gamma3(const float x[3], const Mats& M, float lg[3]) {
    float ratio[3], invd[3];
#pragma unroll
    for (int i = 0; i < 3; ++i) {
        float d = x[0] * M.G[0][i] + x[1] * M.G[1][i] + x[2] * M.G[2][i];
        d = fmaxf(d, EPS);
        float A = x[0] * M.tG[0][i] + x[1] * M.tG[1][i] + x[2] * M.tG[2][i];
        float inv = fast_rcp(d);
        invd[i] = inv;
        ratio[i] = A * inv;
    }
#pragma unroll
    for (int i = 0; i < 3; ++i) {
        float s = ratio[i];
#pragma unroll
        for (int j = 0; j < 3; ++j) {
            s += x[j] * M.G[i][j] * invd[j] * (M.tau[i][j] - ratio[j]);
        }
        lg[i] = clipf(s, -LN_CLIP, LN_CLIP);
    }
}

__device__ __forceinline__ void renorm3(float x[3]) {
    x[0] = fmaxf(x[0], 0.0f);
    x[1] = fmaxf(x[1], 0.0f);
    x[2] = fmaxf(x[2], 0.0f);
    float inv = fast_rcp(fmaxf(x[0] + x[1] + x[2], EPS));
    x[0] *= inv; x[1] *= inv; x[2] *= inv;
}

__global__ __launch_bounds__(256) void nrtl_loss_kernel(
    const float* __restrict__ pred,   // (B,6)
    const float* __restrict__ target, // (B,6)
    const float* __restrict__ Tarr,   // (B,)
    const float* __restrict__ g,      // (B,3,3)
    const float* __restrict__ dirs,   // (2,B,3)
    const float* __restrict__ noise,  // (4,B,3)
    float* __restrict__ partials, int B)
{
    const int i = blockIdx.x * blockDim.x + threadIdx.x;
    float contrib = 0.0f;

    if (i < B) {
        const float* prow = pred   + (size_t)i * 6;
        const float* trow = target + (size_t)i * 6;
        const float* grow = g      + (size_t)i * 9;

        // ---- supervised MSE (v2f NT loads; rows 8B-aligned) ----
        v2f p01 = nt_load2(prow);
        v2f p23 = nt_load2(prow + 2);
        v2f p45 = nt_load2(prow + 4);
        v2f t01 = nt_load2(trow);
        v2f t23 = nt_load2(trow + 2);
        v2f t45 = nt_load2(trow + 4);

        float sup;
        {
            float d0 = p01.x - t01.x, d1 = p01.y - t01.y;
            float d2 = p23.x - t23.x, d3 = p23.y - t23.y;
            float d4 = p45.x - t45.x, d5 = p45.y - t45.y;
            sup = d0 * d0 + d1 * d1 + d2 * d2 + d3 * d3 + d4 * d4 + d5 * d5;
        }

        float xE[3] = {p01.x, p01.y, p23.x};
        float xR[3] = {p23.y, p45.x, p45.y};
        renorm3(xE);
        renorm3(xR);

        const float Tc = fmaxf(nt_load(Tarr + i), 1.0f);
        const float invRT = fast_rcp(R_GAS * Tc);
        Mats M;
#pragma unroll
        for (int a = 0; a < 3; ++a) {
#pragma unroll
            for (int b = 0; b < 3; ++b) {
                float ta = clipf(nt_load(grow + a * 3 + b) * invRT, -TAU_CLIP, TAU_CLIP);
                float Gv = __builtin_amdgcn_exp2f((-ALPHA * LOG2E) * ta);
                M.tau[a][b] = ta;
                M.G[a][b]   = Gv;
                M.tG[a][b]  = ta * Gv;
            }
        }

        float lgE[3], lgR[3];
        ln_gamma3(xE, M, lgE);
        ln_gamma3(xR, M, lgR);

        float logxE[3];
        float phy = 0.0f;
#pragma unroll
        for (int k = 0; k < 3; ++k) {
            logxE[k] = LN2 * __builtin_amdgcn_logf(fmaxf(xE[k], EPS));
            float logxR = LN2 * __builtin_amdgcn_logf(fmaxf(xR[k], EPS));
            float r = logxE[k] + lgE[k] - logxR - lgR[k];
            phy += r * r;
        }

        float gdsum = 0.0f;
#pragma unroll
        for (int d = 0; d < 2; ++d) {
            const float* drow = dirs + ((size_t)d * B + i) * 3;
            float dv[3];
#pragma unroll
            for (int k = 0; k < 3; ++k) dv[k] = nt_load(drow + k);
            float xp[3], xm[3];
#pragma unroll
            for (int k = 0; k < 3; ++k) {
                xp[k] = xE[k] + EPS_FD * dv[k];
                xm[k] = xE[k] - EPS_FD * dv[k];
            }
            renorm3(xp);
            renorm3(xm);
            float lgp[3], lgm[3];
            ln_gamma3(xp, M, lgp);
            ln_gamma3(xm, M, lgm);
            float gd = 0.0f;
            const float inv2e = 0.5f / EPS_FD;
#pragma unroll
            for (int k = 0; k < 3; ++k) gd += xE[k] * ((lgp[k] - lgm[k]) * inv2e);
            gdsum += gd * gd;
        }

        float tpdsum = 0.0f;
#pragma unroll
        for (int tr = 0; tr < 4; ++tr) {
            const float* nrow = noise + ((size_t)tr * B + i) * 3;
            float w[3];
#pragma unroll
            for (int k = 0; k < 3; ++k) w[k] = xE[k] + nt_load(nrow + k);
            renorm3(w);
            float lgw[3];
            ln_gamma3(w, M, lgw);
            float tpd = 0.0f;
#pragma unroll
            for (int k = 0; k < 3; ++k) {
                float logw = LN2 * __builtin_amdgcn_logf(fmaxf(w[k], EPS));
                tpd += w[k] * (logw + lgw[k] - logxE[k] - lgE[k]);
            }
            tpdsum += fmaxf(-tpd, 0.0f);  // MARGIN = 0
        }

        const float invB = 1.0f / (float)B;
        contrib = invB * (sup * (1.0f / 6.0f)
                          + phy * (1.0f / 3.0f)
                          + 0.05f * gdsum
                          + 0.025f * tpdsum);
    }

    // ---- block reduction: wave shuffle then LDS across 4 waves ----
#pragma unroll
    for (int off = 32; off > 0; off >>= 1)
        contrib += __shfl_down(contrib, off, 64);

    __shared__ float ssum[4];
    const int lane = threadIdx.x & 63;
    const int wid  = threadIdx.x >> 6;
    if (lane == 0) ssum[wid] = contrib;
    __syncthreads();
    if (threadIdx.x == 0) {
        partials[blockIdx.x] = ssum[0] + ssum[1] + ssum[2] + ssum[3];
    }
}

__global__ __launch_bounds__(256) void reduce_kernel(
    const float* __restrict__ partials, int n, float* __restrict__ out)
{
    double sacc = 0.0;
    for (int j = threadIdx.x; j < n; j += 256) sacc += (double)partials[j];
#pragma unroll
    for (int off = 32; off > 0; off >>= 1)
        sacc += __shfl_down(sacc, off, 64);
    __shared__ double ds[4];
    const int lane = threadIdx.x & 63;
    const int wid  = threadIdx.x >> 6;
    if (lane == 0) ds[wid] = sacc;
    __syncthreads();
    if (threadIdx.x == 0) out[0] = (float)(ds[0] + ds[1] + ds[2] + ds[3]);
}

extern "C" void kernel_launch(void* const* d_in, const int* in_sizes, int n_in,
                              void* d_out, int out_size, void* d_ws, size_t ws_size,
                              hipStream_t stream) {
    const float* pred   = (const float*)d_in[0];
    const float* target = (const float*)d_in[1];
    const float* Tarr   = (const float*)d_in[2];
    const float* g      = (const float*)d_in[3];
    const float* dirs   = (const float*)d_in[4];
    const float* noise  = (const float*)d_in[5];
    const int B = in_sizes[2];  // T is (B,)

    float* partials = (float*)d_ws;
    float* out      = (float*)d_out;

    const int block = 256;
    const int grid  = (B + block - 1) / block;
    nrtl_loss_kernel<<<grid, block, 0, stream>>>(pred, target, Tarr, g, dirs, noise, partials, B);
    reduce_kernel<<<1, block, 0, stream>>>(partials, grid, out);
}